// Round 1
// baseline (3172.855 us; speedup 1.0000x reference)
//
#include <hip/hip_runtime.h>

typedef unsigned short u16;
typedef unsigned int   u32;
typedef short s16x8 __attribute__((ext_vector_type(8)));
typedef float f32x4 __attribute__((ext_vector_type(4)));

#define AS1 __attribute__((address_space(1)))
#define AS3 __attribute__((address_space(3)))

__device__ __forceinline__ float bf2f(u16 h) {
    union { u32 u; float f; } v; v.u = ((u32)h) << 16; return v.f;
}
__device__ __forceinline__ u16 f2bf(float f) {
    union { float f; u32 u; } v; v.f = f;
    u32 r = (v.u + 0x7FFFu + ((v.u >> 16) & 1u)) >> 16;
    return (u16)r;
}

// ---------- transpose f32 [R][C] -> bf16 [C][R] ----------
__global__ __launch_bounds__(256) void k_transpose_f32_to_bf16T(
    const float* __restrict__ in, u16* __restrict__ out, int R, int C)
{
    __shared__ u16 t[32][33];
    int tx = threadIdx.x & 31, ty = threadIdx.x >> 5;
    int c0 = blockIdx.x * 32, r0 = blockIdx.y * 32;
    #pragma unroll
    for (int i = 0; i < 32; i += 8)
        t[ty + i][tx] = f2bf(in[(size_t)(r0 + ty + i) * C + (c0 + tx)]);
    __syncthreads();
    #pragma unroll
    for (int i = 0; i < 32; i += 8)
        out[(size_t)(c0 + ty + i) * R + (r0 + tx)] = t[tx][ty + i];
}

// ---------- gather embedding rows f32 -> bf16; out row = s*32 + b; ids [32][S] ----------
__global__ __launch_bounds__(256) void k_gather(
    const int* __restrict__ ids, const float* __restrict__ table,
    u16* __restrict__ out, int S)
{
    int row = blockIdx.x;
    int s = row >> 5, b = row & 31;
    int idx = ids[b * S + s];
    const float* src = table + (size_t)idx * 512;
    u16* dst = out + (size_t)row * 512;
    int i = threadIdx.x * 2;
    u32 lo = f2bf(src[i]);
    u32 hi = f2bf(src[i + 1]);
    *(u32*)(dst + i) = lo | (hi << 16);
}

// ---------- m97-style 128x128 GEMM, A [M,512] bf16, Bt [N,512] bf16, f32 out + bias ----------
__global__ __launch_bounds__(256) void k_gemm_xg(
    const u16* __restrict__ A, const u16* __restrict__ Bt,
    const float* __restrict__ bias, float* __restrict__ C, int N)
{
    const int K = 512;
    __shared__ u16 sA[128 * 32];
    __shared__ u16 sB[128 * 32];
    int tid = threadIdx.x;
    int wave = tid >> 6, lane = tid & 63;
    int wm = wave >> 1, wn = wave & 1;
    int r = lane & 15, kseg = (lane >> 4) * 8;
    const u16* Ab = A + (size_t)blockIdx.y * 128 * K;
    const u16* Bb = Bt + (size_t)blockIdx.x * 128 * K;
    f32x4 acc[4][4];
    f32x4 z = {0.f, 0.f, 0.f, 0.f};
    for (int mt = 0; mt < 4; ++mt)
        for (int nt = 0; nt < 4; ++nt) acc[mt][nt] = z;

    for (int kt = 0; kt < K; kt += 32) {
        __syncthreads();
        #pragma unroll
        for (int s = 0; s < 2; ++s) {
            int e = (s * 256 + tid) * 8;
            int row = e >> 5, kk = e & 31;
            __builtin_amdgcn_global_load_lds(
                (const AS1 void*)(Ab + (size_t)row * K + kt + kk),
                (AS3 void*)((char*)sA + s * 4096 + wave * 1024), 16, 0, 0);
            __builtin_amdgcn_global_load_lds(
                (const AS1 void*)(Bb + (size_t)row * K + kt + kk),
                (AS3 void*)((char*)sB + s * 4096 + wave * 1024), 16, 0, 0);
        }
        __syncthreads();
        s16x8 a[4], b[4];
        #pragma unroll
        for (int mt = 0; mt < 4; ++mt)
            a[mt] = *(const s16x8*)(sA + (wm * 64 + mt * 16 + r) * 32 + kseg);
        #pragma unroll
        for (int nt = 0; nt < 4; ++nt)
            b[nt] = *(const s16x8*)(sB + (wn * 64 + nt * 16 + r) * 32 + kseg);
        #pragma unroll
        for (int mt = 0; mt < 4; ++mt)
            #pragma unroll
            for (int nt = 0; nt < 4; ++nt)
                acc[mt][nt] = __builtin_amdgcn_mfma_f32_16x16x32_bf16(a[mt], b[nt], acc[mt][nt], 0, 0, 0);
    }
    int mrow0 = (lane >> 4) * 4;
    #pragma unroll
    for (int mt = 0; mt < 4; ++mt) {
        #pragma unroll
        for (int nt = 0; nt < 4; ++nt) {
            int m = blockIdx.y * 128 + wm * 64 + mt * 16 + mrow0;
            int n = blockIdx.x * 128 + wn * 64 + nt * 16 + r;
            float bv = bias[n];
            #pragma unroll
            for (int q = 0; q < 4; ++q)
                C[(size_t)(m + q) * N + n] = acc[mt][nt][q] + bv;
        }
    }
}

// ---------- logits GEMM: same structure; writes f32 to d_out with [t,b]->[b,t] row remap ----------
__global__ __launch_bounds__(256) void k_gemm_logits(
    const u16* __restrict__ A, const u16* __restrict__ Bt,
    const float* __restrict__ bias, float* __restrict__ C)
{
    const int K = 512, N = 32000;
    __shared__ u16 sA[128 * 32];
    __shared__ u16 sB[128 * 32];
    int tid = threadIdx.x;
    int wave = tid >> 6, lane = tid & 63;
    int wm = wave >> 1, wn = wave & 1;
    int r = lane & 15, kseg = (lane >> 4) * 8;
    const u16* Ab = A + (size_t)blockIdx.y * 128 * K;
    const u16* Bb = Bt + (size_t)blockIdx.x * 128 * K;
    f32x4 acc[4][4];
    f32x4 z = {0.f, 0.f, 0.f, 0.f};
    for (int mt = 0; mt < 4; ++mt)
        for (int nt = 0; nt < 4; ++nt) acc[mt][nt] = z;

    for (int kt = 0; kt < K; kt += 32) {
        __syncthreads();
        #pragma unroll
        for (int s = 0; s < 2; ++s) {
            int e = (s * 256 + tid) * 8;
            int row = e >> 5, kk = e & 31;
            __builtin_amdgcn_global_load_lds(
                (const AS1 void*)(Ab + (size_t)row * K + kt + kk),
                (AS3 void*)((char*)sA + s * 4096 + wave * 1024), 16, 0, 0);
            __builtin_amdgcn_global_load_lds(
                (const AS1 void*)(Bb + (size_t)row * K + kt + kk),
                (AS3 void*)((char*)sB + s * 4096 + wave * 1024), 16, 0, 0);
        }
        __syncthreads();
        s16x8 a[4], b[4];
        #pragma unroll
        for (int mt = 0; mt < 4; ++mt)
            a[mt] = *(const s16x8*)(sA + (wm * 64 + mt * 16 + r) * 32 + kseg);
        #pragma unroll
        for (int nt = 0; nt < 4; ++nt)
            b[nt] = *(const s16x8*)(sB + (wn * 64 + nt * 16 + r) * 32 + kseg);
        #pragma unroll
        for (int mt = 0; mt < 4; ++mt)
            #pragma unroll
            for (int nt = 0; nt < 4; ++nt)
                acc[mt][nt] = __builtin_amdgcn_mfma_f32_16x16x32_bf16(a[mt], b[nt], acc[mt][nt], 0, 0, 0);
    }
    int mrow0 = (lane >> 4) * 4;
    #pragma unroll
    for (int mt = 0; mt < 4; ++mt) {
        #pragma unroll
        for (int nt = 0; nt < 4; ++nt) {
            int n = blockIdx.x * 128 + wn * 64 + nt * 16 + r;
            float bv = bias[n];
            #pragma unroll
            for (int q = 0; q < 4; ++q) {
                int m = blockIdx.y * 128 + wm * 64 + mt * 16 + mrow0 + q;  // m = t*32 + b
                int row2 = (m & 31) * 64 + (m >> 5);                        // b*64 + t
                C[(size_t)row2 * N + n] = acc[mt][nt][q] + bv;
            }
        }
    }
}

// ---------- one LSTM step: g = xg_t + h@Uh + bh ; gates ; h,c update ----------
// grid 16 blocks x 256 thr. Block covers j-slice of 32 (x 4 gates). UhT [2048][512] bf16.
__global__ __launch_bounds__(256) void k_lstm_step(
    const u16* __restrict__ h_in, u16* __restrict__ h_out,
    float* __restrict__ c, const float* __restrict__ xg_t,
    const u16* __restrict__ UhT, const float* __restrict__ bh,
    u16* __restrict__ hs_out)
{
    int tid = threadIdx.x, lane = tid & 63, wave = tid >> 6;
    int wm = wave >> 1, wj = wave & 1;
    int j16 = blockIdx.x * 32 + wj * 16;
    int m0 = wm * 16;
    int r = lane & 15, kseg = (lane >> 4) * 8;
    f32x4 z = {0.f, 0.f, 0.f, 0.f};
    f32x4 acc[4] = {z, z, z, z};
    int arow = m0 + r;
    for (int kt = 0; kt < 512; kt += 32) {
        s16x8 a = *(const s16x8*)(h_in + arow * 512 + kt + kseg);
        #pragma unroll
        for (int g = 0; g < 4; ++g) {
            int n = g * 512 + j16 + r;
            s16x8 b = *(const s16x8*)(UhT + (size_t)n * 512 + kt + kseg);
            acc[g] = __builtin_amdgcn_mfma_f32_16x16x32_bf16(a, b, acc[g], 0, 0, 0);
        }
    }
    #pragma unroll
    for (int q = 0; q < 4; ++q) {
        int b = m0 + (lane >> 4) * 4 + q;
        int j = j16 + r;
        float gi = acc[0][q] + xg_t[b * 2048 + j]        + bh[j];
        float gf = acc[1][q] + xg_t[b * 2048 + 512 + j]  + bh[512 + j];
        float gG = acc[2][q] + xg_t[b * 2048 + 1024 + j] + bh[1024 + j];
        float go = acc[3][q] + xg_t[b * 2048 + 1536 + j] + bh[1536 + j];
        float iv = 1.f / (1.f + expf(-gi));
        float fv = 1.f / (1.f + expf(-gf));
        float gv = tanhf(gG);
        float ov = 1.f / (1.f + expf(-go));
        float cn = fv * c[b * 512 + j] + iv * gv;
        c[b * 512 + j] = cn;
        float hn = ov * tanhf(cn);
        u16 hb = f2bf(hn);
        h_out[b * 512 + j] = hb;
        if (hs_out) hs_out[b * 512 + j] = hb;
    }
}

// ---------- in-place row log-softmax over V=32000 ----------
__global__ __launch_bounds__(256) void k_logsoftmax(float* __restrict__ out)
{
    __shared__ float red[8];
    int row = blockIdx.x;
    float* rp = out + (size_t)row * 32000;
    int tid = threadIdx.x, lane = tid & 63, wave = tid >> 6;
    float m = -1e30f;
    for (int i = tid; i < 32000; i += 256) m = fmaxf(m, rp[i]);
    #pragma unroll
    for (int o = 32; o; o >>= 1) m = fmaxf(m, __shfl_down(m, o));
    if (lane == 0) red[wave] = m;
    __syncthreads();
    m = fmaxf(fmaxf(red[0], red[1]), fmaxf(red[2], red[3]));
    float s = 0.f;
    for (int i = tid; i < 32000; i += 256) s += expf(rp[i] - m);
    #pragma unroll
    for (int o = 32; o; o >>= 1) s += __shfl_down(s, o);
    if (lane == 0) red[4 + wave] = s;
    __syncthreads();
    float lse = m + logf(red[4] + red[5] + red[6] + red[7]);
    for (int i = tid; i < 32000; i += 256) rp[i] = rp[i] - lse;
}

extern "C" void kernel_launch(void* const* d_in, const int* in_sizes, int n_in,
                              void* d_out, int out_size, void* d_ws, size_t ws_size,
                              hipStream_t stream)
{
    const int*   src       = (const int*)d_in[0];
    const int*   tgt       = (const int*)d_in[1];
    const float* enc_embed = (const float*)d_in[2];
    const float* enc_Wx    = (const float*)d_in[3];
    const float* enc_bx    = (const float*)d_in[4];
    const float* enc_Uh    = (const float*)d_in[5];
    const float* enc_bh    = (const float*)d_in[6];
    const float* dec_embed = (const float*)d_in[7];
    const float* dec_Wx    = (const float*)d_in[8];
    const float* dec_bx    = (const float*)d_in[9];
    const float* dec_Uh    = (const float*)d_in[10];
    const float* dec_bh    = (const float*)d_in[11];
    const float* out_W     = (const float*)d_in[12];
    const float* out_b     = (const float*)d_in[13];
    float* out = (float*)d_out;

    char* ws = (char*)d_ws;
    size_t off = 0;
    auto alloc = [&](size_t bytes) { void* p = ws + off; off += (bytes + 255) & ~(size_t)255; return p; };
    u16*   WoT  = (u16*)alloc(32000ull * 512 * 2);
    u16*   WxTe = (u16*)alloc(2048ull * 512 * 2);
    u16*   UhTe = (u16*)alloc(2048ull * 512 * 2);
    u16*   WxTd = (u16*)alloc(2048ull * 512 * 2);
    u16*   UhTd = (u16*)alloc(2048ull * 512 * 2);
    u16*   embE = (u16*)alloc(4096ull * 512 * 2);
    u16*   embD = (u16*)alloc(2048ull * 512 * 2);
    float* xgE  = (float*)alloc(4096ull * 2048 * 4);
    float* xgD  = (float*)alloc(2048ull * 2048 * 4);
    u16*   hbuf = (u16*)alloc(2ull * 32 * 512 * 2);
    float* cbuf = (float*)alloc(32ull * 512 * 4);
    u16*   hs   = (u16*)alloc(64ull * 32 * 512 * 2);

    // weight transposes f32 [K][N] -> bf16 [N][K]
    k_transpose_f32_to_bf16T<<<dim3(1000, 16), 256, 0, stream>>>(out_W, WoT, 512, 32000);
    k_transpose_f32_to_bf16T<<<dim3(64, 16),   256, 0, stream>>>(enc_Wx, WxTe, 512, 2048);
    k_transpose_f32_to_bf16T<<<dim3(64, 16),   256, 0, stream>>>(enc_Uh, UhTe, 512, 2048);
    k_transpose_f32_to_bf16T<<<dim3(64, 16),   256, 0, stream>>>(dec_Wx, WxTd, 512, 2048);
    k_transpose_f32_to_bf16T<<<dim3(64, 16),   256, 0, stream>>>(dec_Uh, UhTd, 512, 2048);
    // embedding gathers
    k_gather<<<4096, 256, 0, stream>>>(src, enc_embed, embE, 128);
    k_gather<<<2048, 256, 0, stream>>>(tgt, dec_embed, embD, 64);
    // input projections: xg = emb @ Wx + bx
    k_gemm_xg<<<dim3(16, 32), 256, 0, stream>>>(embE, WxTe, enc_bx, xgE, 2048);
    k_gemm_xg<<<dim3(16, 16), 256, 0, stream>>>(embD, WxTd, dec_bx, xgD, 2048);
    // init h0, c0
    hipMemsetAsync(hbuf, 0, 32 * 512 * 2, stream);
    hipMemsetAsync(cbuf, 0, 32 * 512 * 4, stream);
    // encoder scan
    for (int t = 0; t < 128; ++t)
        k_lstm_step<<<16, 256, 0, stream>>>(hbuf + (t & 1) * (32 * 512),
                                            hbuf + ((t + 1) & 1) * (32 * 512),
                                            cbuf, xgE + (size_t)t * 32 * 2048,
                                            UhTe, enc_bh, (u16*)nullptr);
    // decoder scan (teacher forced), record hs
    for (int t = 0; t < 64; ++t)
        k_lstm_step<<<16, 256, 0, stream>>>(hbuf + (t & 1) * (32 * 512),
                                            hbuf + ((t + 1) & 1) * (32 * 512),
                                            cbuf, xgD + (size_t)t * 32 * 2048,
                                            UhTd, dec_bh, hs + (size_t)t * 32 * 512);
    // logits into d_out (with [t,b]->[b,t] remap + bias), then in-place log-softmax
    k_gemm_logits<<<dim3(250, 16), 256, 0, stream>>>(hs, WoT, out_b, out);
    k_logsoftmax<<<2048, 256, 0, stream>>>(out);
}

// Round 3
// 2732.209 us; speedup vs baseline: 1.1613x; 1.1613x over previous
//
#include <hip/hip_runtime.h>

typedef unsigned short u16;
typedef unsigned int   u32;
typedef short s16x8 __attribute__((ext_vector_type(8)));
typedef float f32x4 __attribute__((ext_vector_type(4)));

#define AS1 __attribute__((address_space(1)))
#define AS3 __attribute__((address_space(3)))

__device__ __forceinline__ float bf2f(u16 h) {
    union { u32 u; float f; } v; v.u = ((u32)h) << 16; return v.f;
}
__device__ __forceinline__ u16 f2bf(float f) {
    union { float f; u32 u; } v; v.f = f;
    u32 r = (v.u + 0x7FFFu + ((v.u >> 16) & 1u)) >> 16;
    return (u16)r;
}

// ---------- transpose f32 [R][C] -> bf16 [C][R] ----------
__global__ __launch_bounds__(256) void k_transpose_f32_to_bf16T(
    const float* __restrict__ in, u16* __restrict__ out, int R, int C)
{
    __shared__ u16 t[32][33];
    int tx = threadIdx.x & 31, ty = threadIdx.x >> 5;
    int c0 = blockIdx.x * 32, r0 = blockIdx.y * 32;
    #pragma unroll
    for (int i = 0; i < 32; i += 8)
        t[ty + i][tx] = f2bf(in[(size_t)(r0 + ty + i) * C + (c0 + tx)]);
    __syncthreads();
    #pragma unroll
    for (int i = 0; i < 32; i += 8)
        out[(size_t)(c0 + ty + i) * R + (r0 + tx)] = t[tx][ty + i];
}

// ---------- gather embedding rows f32 -> bf16; out row = s*32 + b; ids [32][S] ----------
__global__ __launch_bounds__(256) void k_gather(
    const int* __restrict__ ids, const float* __restrict__ table,
    u16* __restrict__ out, int S)
{
    int row = blockIdx.x;
    int s = row >> 5, b = row & 31;
    int idx = ids[b * S + s];
    const float* src = table + (size_t)idx * 512;
    u16* dst = out + (size_t)row * 512;
    int i = threadIdx.x * 2;
    u32 lo = f2bf(src[i]);
    u32 hi = f2bf(src[i + 1]);
    *(u32*)(dst + i) = lo | (hi << 16);
}

// ---------- m97-style 128x128 GEMM, A [M,512] bf16, Bt [N,512] bf16, f32 out + bias ----------
__global__ __launch_bounds__(256) void k_gemm_xg(
    const u16* __restrict__ A, const u16* __restrict__ Bt,
    const float* __restrict__ bias, float* __restrict__ C, int N)
{
    const int K = 512;
    __shared__ u16 sA[128 * 32];
    __shared__ u16 sB[128 * 32];
    int tid = threadIdx.x;
    int wave = tid >> 6, lane = tid & 63;
    int wm = wave >> 1, wn = wave & 1;
    int r = lane & 15, kseg = (lane >> 4) * 8;
    const u16* Ab = A + (size_t)blockIdx.y * 128 * K;
    const u16* Bb = Bt + (size_t)blockIdx.x * 128 * K;
    f32x4 acc[4][4];
    f32x4 z = {0.f, 0.f, 0.f, 0.f};
    for (int mt = 0; mt < 4; ++mt)
        for (int nt = 0; nt < 4; ++nt) acc[mt][nt] = z;

    for (int kt = 0; kt < K; kt += 32) {
        __syncthreads();
        #pragma unroll
        for (int s = 0; s < 2; ++s) {
            int e = (s * 256 + tid) * 8;
            int row = e >> 5, kk = e & 31;
            __builtin_amdgcn_global_load_lds(
                (const AS1 void*)(Ab + (size_t)row * K + kt + kk),
                (AS3 void*)((char*)sA + s * 4096 + wave * 1024), 16, 0, 0);
            __builtin_amdgcn_global_load_lds(
                (const AS1 void*)(Bb + (size_t)row * K + kt + kk),
                (AS3 void*)((char*)sB + s * 4096 + wave * 1024), 16, 0, 0);
        }
        __syncthreads();
        s16x8 a[4], b[4];
        #pragma unroll
        for (int mt = 0; mt < 4; ++mt)
            a[mt] = *(const s16x8*)(sA + (wm * 64 + mt * 16 + r) * 32 + kseg);
        #pragma unroll
        for (int nt = 0; nt < 4; ++nt)
            b[nt] = *(const s16x8*)(sB + (wn * 64 + nt * 16 + r) * 32 + kseg);
        #pragma unroll
        for (int mt = 0; mt < 4; ++mt)
            #pragma unroll
            for (int nt = 0; nt < 4; ++nt)
                acc[mt][nt] = __builtin_amdgcn_mfma_f32_16x16x32_bf16(a[mt], b[nt], acc[mt][nt], 0, 0, 0);
    }
    int mrow0 = (lane >> 4) * 4;
    #pragma unroll
    for (int mt = 0; mt < 4; ++mt) {
        #pragma unroll
        for (int nt = 0; nt < 4; ++nt) {
            int m = blockIdx.y * 128 + wm * 64 + mt * 16 + mrow0;
            int n = blockIdx.x * 128 + wn * 64 + nt * 16 + r;
            float bv = bias[n];
            #pragma unroll
            for (int q = 0; q < 4; ++q)
                C[(size_t)(m + q) * N + n] = acc[mt][nt][q] + bv;
        }
    }
}

// ---------- logits GEMM: writes f32 to d_out with [t,b]->[b,t] row remap ----------
__global__ __launch_bounds__(256) void k_gemm_logits(
    const u16* __restrict__ A, const u16* __restrict__ Bt,
    const float* __restrict__ bias, float* __restrict__ C)
{
    const int K = 512, N = 32000;
    __shared__ u16 sA[128 * 32];
    __shared__ u16 sB[128 * 32];
    int tid = threadIdx.x;
    int wave = tid >> 6, lane = tid & 63;
    int wm = wave >> 1, wn = wave & 1;
    int r = lane & 15, kseg = (lane >> 4) * 8;
    const u16* Ab = A + (size_t)blockIdx.y * 128 * K;
    const u16* Bb = Bt + (size_t)blockIdx.x * 128 * K;
    f32x4 acc[4][4];
    f32x4 z = {0.f, 0.f, 0.f, 0.f};
    for (int mt = 0; mt < 4; ++mt)
        for (int nt = 0; nt < 4; ++nt) acc[mt][nt] = z;

    for (int kt = 0; kt < K; kt += 32) {
        __syncthreads();
        #pragma unroll
        for (int s = 0; s < 2; ++s) {
            int e = (s * 256 + tid) * 8;
            int row = e >> 5, kk = e & 31;
            __builtin_amdgcn_global_load_lds(
                (const AS1 void*)(Ab + (size_t)row * K + kt + kk),
                (AS3 void*)((char*)sA + s * 4096 + wave * 1024), 16, 0, 0);
            __builtin_amdgcn_global_load_lds(
                (const AS1 void*)(Bb + (size_t)row * K + kt + kk),
                (AS3 void*)((char*)sB + s * 4096 + wave * 1024), 16, 0, 0);
        }
        __syncthreads();
        s16x8 a[4], b[4];
        #pragma unroll
        for (int mt = 0; mt < 4; ++mt)
            a[mt] = *(const s16x8*)(sA + (wm * 64 + mt * 16 + r) * 32 + kseg);
        #pragma unroll
        for (int nt = 0; nt < 4; ++nt)
            b[nt] = *(const s16x8*)(sB + (wn * 64 + nt * 16 + r) * 32 + kseg);
        #pragma unroll
        for (int mt = 0; mt < 4; ++mt)
            #pragma unroll
            for (int nt = 0; nt < 4; ++nt)
                acc[mt][nt] = __builtin_amdgcn_mfma_f32_16x16x32_bf16(a[mt], b[nt], acc[mt][nt], 0, 0, 0);
    }
    int mrow0 = (lane >> 4) * 4;
    #pragma unroll
    for (int mt = 0; mt < 4; ++mt) {
        #pragma unroll
        for (int nt = 0; nt < 4; ++nt) {
            int n = blockIdx.x * 128 + wn * 64 + nt * 16 + r;
            float bv = bias[n];
            #pragma unroll
            for (int q = 0; q < 4; ++q) {
                int m = blockIdx.y * 128 + wm * 64 + mt * 16 + mrow0 + q;  // m = t*32 + b
                int row2 = (m & 31) * 64 + (m >> 5);                        // b*64 + t
                C[(size_t)row2 * N + n] = acc[mt][nt][q] + bv;
            }
        }
    }
}

// ---------- persistent LSTM scan: encoder (T=128) + decoder (T=64) in one kernel ----------
// 16 blocks x 256 threads. Block owns j-slice of 32 cols; wave g owns gate g.
// Uh slice lives in registers (B[16][2], 128 VGPRs); c lives in 4 VGPRs/thread.
// h crosses blocks via ping-pong global + device-scope grid barrier.
__global__ __launch_bounds__(256, 1) void k_scan(
    const u16* __restrict__ UhTe, const u16* __restrict__ UhTd,
    const float* __restrict__ xgE, const float* __restrict__ xgD,
    const float* __restrict__ bhE, const float* __restrict__ bhD,
    u16* __restrict__ hping, u16* __restrict__ hs, int* __restrict__ bar)
{
    int tid = threadIdx.x, lane = tid & 63, g = tid >> 6;
    int blk = blockIdx.x;
    int r = lane & 15, hi = lane >> 4, kseg = hi * 8;
    int jbase = blk * 32;
    __shared__ float gsm[4][32][33];
    float cr[4] = {0.f, 0.f, 0.f, 0.f};
    int eb = tid >> 3;             // epilogue row b (0..31)
    int ejq = (tid & 7) * 4;       // epilogue col offset within slice (4 cols)
    int st = 0;
    for (int phase = 0; phase < 2; ++phase) {
        const u16*  UhT = phase ? UhTd : UhTe;
        const float* xg = phase ? xgD : xgE;
        const float* bh = phase ? bhD : bhE;
        int T = phase ? 64 : 128;
        s16x8 B[16][2];
        #pragma unroll
        for (int kt = 0; kt < 16; ++kt)
            #pragma unroll
            for (int nt = 0; nt < 2; ++nt)
                B[kt][nt] = *(const s16x8*)(UhT +
                    (size_t)(g * 512 + jbase + nt * 16 + r) * 512 + kt * 32 + kseg);
        float4 bhv[4];
        #pragma unroll
        for (int gg = 0; gg < 4; ++gg)
            bhv[gg] = *(const float4*)(bh + gg * 512 + jbase + ejq);

        for (int t = 0; t < T; ++t, ++st) {
            const u16* hin = hping + (st & 1) * (32 * 512);
            u16* hout = hping + ((st + 1) & 1) * (32 * 512);
            f32x4 z = {0.f, 0.f, 0.f, 0.f};
            f32x4 acc[2][2] = {{z, z}, {z, z}};
            #pragma unroll
            for (int kt = 0; kt < 16; ++kt) {
                s16x8 a0 = *(const s16x8*)(hin + r * 512 + kt * 32 + kseg);
                s16x8 a1 = *(const s16x8*)(hin + (16 + r) * 512 + kt * 32 + kseg);
                acc[0][0] = __builtin_amdgcn_mfma_f32_16x16x32_bf16(a0, B[kt][0], acc[0][0], 0, 0, 0);
                acc[0][1] = __builtin_amdgcn_mfma_f32_16x16x32_bf16(a0, B[kt][1], acc[0][1], 0, 0, 0);
                acc[1][0] = __builtin_amdgcn_mfma_f32_16x16x32_bf16(a1, B[kt][0], acc[1][0], 0, 0, 0);
                acc[1][1] = __builtin_amdgcn_mfma_f32_16x16x32_bf16(a1, B[kt][1], acc[1][1], 0, 0, 0);
            }
            #pragma unroll
            for (int mt = 0; mt < 2; ++mt)
                #pragma unroll
                for (int nt = 0; nt < 2; ++nt)
                    #pragma unroll
                    for (int q = 0; q < 4; ++q)
                        gsm[g][mt * 16 + hi * 4 + q][nt * 16 + r] = acc[mt][nt][q];
            __syncthreads();
            // epilogue: recombine gates, update c (registers), emit h
            const float* xgt = xg + (size_t)t * 32 * 2048 + eb * 2048 + jbase + ejq;
            float4 xv0 = *(const float4*)(xgt);
            float4 xv1 = *(const float4*)(xgt + 512);
            float4 xv2 = *(const float4*)(xgt + 1024);
            float4 xv3 = *(const float4*)(xgt + 1536);
            u16 hnb[4];
            #pragma unroll
            for (int q = 0; q < 4; ++q) {
                float gi = gsm[0][eb][ejq + q] + ((const float*)&xv0)[q] + ((const float*)&bhv[0])[q];
                float gf = gsm[1][eb][ejq + q] + ((const float*)&xv1)[q] + ((const float*)&bhv[1])[q];
                float gG = gsm[2][eb][ejq + q] + ((const float*)&xv2)[q] + ((const float*)&bhv[2])[q];
                float go = gsm[3][eb][ejq + q] + ((const float*)&xv3)[q] + ((const float*)&bhv[3])[q];
                float iv = 1.f / (1.f + expf(-gi));
                float fv = 1.f / (1.f + expf(-gf));
                float gv = tanhf(gG);
                float ov = 1.f / (1.f + expf(-go));
                cr[q] = fv * cr[q] + iv * gv;
                hnb[q] = f2bf(ov * tanhf(cr[q]));
            }
            u32 w0 = (u32)hnb[0] | ((u32)hnb[1] << 16);
            u32 w1 = (u32)hnb[2] | ((u32)hnb[3] << 16);
            u32* hp = (u32*)(hout + eb * 512 + jbase + ejq);
            hp[0] = w0; hp[1] = w1;
            if (phase) {
                u32* hq = (u32*)(hs + (size_t)t * 32 * 512 + eb * 512 + jbase + ejq);
                hq[0] = w0; hq[1] = w1;
            }
            // device-scope grid barrier (release h writes, acquire others')
            __threadfence();
            __syncthreads();
            if (tid == 0) {
                __hip_atomic_fetch_add(bar, 1, __ATOMIC_RELEASE, __HIP_MEMORY_SCOPE_AGENT);
                int tgt = (st + 1) * 16;
                while (__hip_atomic_load(bar, __ATOMIC_ACQUIRE, __HIP_MEMORY_SCOPE_AGENT) < tgt) {}
            }
            __syncthreads();
            __threadfence();
        }
    }
}

// ---------- in-place row log-softmax over V=32000: online max+sum pass, subtract pass ----------
__global__ __launch_bounds__(256) void k_logsoftmax(float* __restrict__ out)
{
    __shared__ float redm[4], reds[4], lses;
    int row = blockIdx.x;
    float4* rp4 = (float4*)(out + (size_t)row * 32000);
    int tid = threadIdx.x, lane = tid & 63, wave = tid >> 6;
    float m = -1e30f, s = 0.f;
    for (int i = tid; i < 8000; i += 256) {
        float4 v = rp4[i];
        float mx = fmaxf(fmaxf(v.x, v.y), fmaxf(v.z, v.w));
        if (mx > m) { s *= expf(m - mx); m = mx; }
        s += expf(v.x - m) + expf(v.y - m) + expf(v.z - m) + expf(v.w - m);
    }
    #pragma unroll
    for (int o = 32; o; o >>= 1) {
        float om = __shfl_down(m, o);
        float os = __shfl_down(s, o);
        float nm = fmaxf(m, om);
        s = s * expf(m - nm) + os * expf(om - nm);
        m = nm;
    }
    if (lane == 0) { redm[wave] = m; reds[wave] = s; }
    __syncthreads();
    if (tid == 0) {
        float M = redm[0], S = reds[0];
        #pragma unroll
        for (int w = 1; w < 4; ++w) {
            float nm = fmaxf(M, redm[w]);
            S = S * expf(M - nm) + reds[w] * expf(redm[w] - nm);
            M = nm;
        }
        lses = M + logf(S);
    }
    __syncthreads();
    float lse = lses;
    for (int i = tid; i < 8000; i += 256) {
        float4 v = rp4[i];
        v.x -= lse; v.y -= lse; v.z -= lse; v.w -= lse;
        rp4[i] = v;
    }
}

extern "C" void kernel_launch(void* const* d_in, const int* in_sizes, int n_in,
                              void* d_out, int out_size, void* d_ws, size_t ws_size,
                              hipStream_t stream)
{
    const int*   src       = (const int*)d_in[0];
    const int*   tgt       = (const int*)d_in[1];
    const float* enc_embed = (const float*)d_in[2];
    const float* enc_Wx    = (const float*)d_in[3];
    const float* enc_bx    = (const float*)d_in[4];
    const float* enc_Uh    = (const float*)d_in[5];
    const float* enc_bh    = (const float*)d_in[6];
    const float* dec_embed = (const float*)d_in[7];
    const float* dec_Wx    = (const float*)d_in[8];
    const float* dec_bx    = (const float*)d_in[9];
    const float* dec_Uh    = (const float*)d_in[10];
    const float* dec_bh    = (const float*)d_in[11];
    const float* out_W     = (const float*)d_in[12];
    const float* out_b     = (const float*)d_in[13];
    float* out = (float*)d_out;

    char* ws = (char*)d_ws;
    size_t off = 0;
    auto alloc = [&](size_t bytes) { void* p = ws + off; off += (bytes + 255) & ~(size_t)255; return p; };
    u16*   WoT  = (u16*)alloc(32000ull * 512 * 2);
    u16*   WxTe = (u16*)alloc(2048ull * 512 * 2);
    u16*   UhTe = (u16*)alloc(2048ull * 512 * 2);
    u16*   WxTd = (u16*)alloc(2048ull * 512 * 2);
    u16*   UhTd = (u16*)alloc(2048ull * 512 * 2);
    u16*   embE = (u16*)alloc(4096ull * 512 * 2);
    u16*   embD = (u16*)alloc(2048ull * 512 * 2);
    float* xgE  = (float*)alloc(4096ull * 2048 * 4);
    float* xgD  = (float*)alloc(2048ull * 2048 * 4);
    u16*   hbuf = (u16*)alloc(2ull * 32 * 512 * 2);
    u16*   hs   = (u16*)alloc(64ull * 32 * 512 * 2);
    int*   bar  = (int*)alloc(256);

    // weight transposes f32 [K][N] -> bf16 [N][K]
    k_transpose_f32_to_bf16T<<<dim3(1000, 16), 256, 0, stream>>>(out_W, WoT, 512, 32000);
    k_transpose_f32_to_bf16T<<<dim3(64, 16),   256, 0, stream>>>(enc_Wx, WxTe, 512, 2048);
    k_transpose_f32_to_bf16T<<<dim3(64, 16),   256, 0, stream>>>(enc_Uh, UhTe, 512, 2048);
    k_transpose_f32_to_bf16T<<<dim3(64, 16),   256, 0, stream>>>(dec_Wx, WxTd, 512, 2048);
    k_transpose_f32_to_bf16T<<<dim3(64, 16),   256, 0, stream>>>(dec_Uh, UhTd, 512, 2048);
    // embedding gathers
    k_gather<<<4096, 256, 0, stream>>>(src, enc_embed, embE, 128);
    k_gather<<<2048, 256, 0, stream>>>(tgt, dec_embed, embD, 64);
    // input projections: xg = emb @ Wx + bx
    k_gemm_xg<<<dim3(16, 32), 256, 0, stream>>>(embE, WxTe, enc_bx, xgE, 2048);
    k_gemm_xg<<<dim3(16, 16), 256, 0, stream>>>(embD, WxTd, dec_bx, xgD, 2048);
    // init h0 and barrier counter
    hipMemsetAsync(hbuf, 0, 2 * 32 * 512 * 2, stream);
    hipMemsetAsync(bar, 0, 256, stream);
    // full recurrence in ONE kernel (128 enc + 64 dec steps)
    k_scan<<<16, 256, 0, stream>>>(UhTe, UhTd, xgE, xgD, enc_bh, dec_bh, hbuf, hs, bar);
    // logits into d_out (with [t,b]->[b,t] remap + bias), then in-place log-softmax
    k_gemm_logits<<<dim3(250, 16), 256, 0, stream>>>(hs, WoT, out_b, out);
    k_logsoftmax<<<2048, 256, 0, stream>>>(out);
}

// Round 4
// 2476.762 us; speedup vs baseline: 1.2810x; 1.1031x over previous
//
#include <hip/hip_runtime.h>

typedef unsigned short u16;
typedef unsigned int   u32;
typedef unsigned long long u64;
typedef short s16x8 __attribute__((ext_vector_type(8)));
typedef float f32x4 __attribute__((ext_vector_type(4)));

#define AS1 __attribute__((address_space(1)))
#define AS3 __attribute__((address_space(3)))

__device__ __forceinline__ u16 f2bf(float f) {
    union { float f; u32 u; } v; v.f = f;
    u32 r = (v.u + 0x7FFFu + ((v.u >> 16) & 1u)) >> 16;
    return (u16)r;
}

// coherent (agent-scope, sc1) 16-byte h load via two 8B relaxed atomics
__device__ __forceinline__ s16x8 load_h16(const u16* p) {
    union { u64 d[2]; s16x8 v; } u;
    u.d[0] = __hip_atomic_load((const u64*)p,     __ATOMIC_RELAXED, __HIP_MEMORY_SCOPE_AGENT);
    u.d[1] = __hip_atomic_load((const u64*)p + 1, __ATOMIC_RELAXED, __HIP_MEMORY_SCOPE_AGENT);
    return u.v;
}

// ---------- transpose f32 [R][C] -> bf16 [C][R] ----------
__global__ __launch_bounds__(256) void k_transpose_f32_to_bf16T(
    const float* __restrict__ in, u16* __restrict__ out, int R, int C)
{
    __shared__ u16 t[32][33];
    int tx = threadIdx.x & 31, ty = threadIdx.x >> 5;
    int c0 = blockIdx.x * 32, r0 = blockIdx.y * 32;
    #pragma unroll
    for (int i = 0; i < 32; i += 8)
        t[ty + i][tx] = f2bf(in[(size_t)(r0 + ty + i) * C + (c0 + tx)]);
    __syncthreads();
    #pragma unroll
    for (int i = 0; i < 32; i += 8)
        out[(size_t)(c0 + ty + i) * R + (r0 + tx)] = t[tx][ty + i];
}

// ---------- gather embedding rows f32 -> bf16; out row = s*32 + b; ids [32][S] ----------
__global__ __launch_bounds__(256) void k_gather(
    const int* __restrict__ ids, const float* __restrict__ table,
    u16* __restrict__ out, int S)
{
    int row = blockIdx.x;
    int s = row >> 5, b = row & 31;
    int idx = ids[b * S + s];
    const float* src = table + (size_t)idx * 512;
    u16* dst = out + (size_t)row * 512;
    int i = threadIdx.x * 2;
    u32 lo = f2bf(src[i]);
    u32 hi = f2bf(src[i + 1]);
    *(u32*)(dst + i) = lo | (hi << 16);
}

// ---------- m97-style 128x128 GEMM, A [M,512] bf16, Bt [N,512] bf16, f32 out + bias ----------
__global__ __launch_bounds__(256) void k_gemm_xg(
    const u16* __restrict__ A, const u16* __restrict__ Bt,
    const float* __restrict__ bias, float* __restrict__ C, int N)
{
    const int K = 512;
    __shared__ u16 sA[128 * 32];
    __shared__ u16 sB[128 * 32];
    int tid = threadIdx.x;
    int wave = tid >> 6, lane = tid & 63;
    int wm = wave >> 1, wn = wave & 1;
    int r = lane & 15, kseg = (lane >> 4) * 8;
    const u16* Ab = A + (size_t)blockIdx.y * 128 * K;
    const u16* Bb = Bt + (size_t)blockIdx.x * 128 * K;
    f32x4 acc[4][4];
    f32x4 z = {0.f, 0.f, 0.f, 0.f};
    for (int mt = 0; mt < 4; ++mt)
        for (int nt = 0; nt < 4; ++nt) acc[mt][nt] = z;

    for (int kt = 0; kt < K; kt += 32) {
        __syncthreads();
        #pragma unroll
        for (int s = 0; s < 2; ++s) {
            int e = (s * 256 + tid) * 8;
            int row = e >> 5, kk = e & 31;
            __builtin_amdgcn_global_load_lds(
                (const AS1 void*)(Ab + (size_t)row * K + kt + kk),
                (AS3 void*)((char*)sA + s * 4096 + wave * 1024), 16, 0, 0);
            __builtin_amdgcn_global_load_lds(
                (const AS1 void*)(Bb + (size_t)row * K + kt + kk),
                (AS3 void*)((char*)sB + s * 4096 + wave * 1024), 16, 0, 0);
        }
        __syncthreads();
        s16x8 a[4], b[4];
        #pragma unroll
        for (int mt = 0; mt < 4; ++mt)
            a[mt] = *(const s16x8*)(sA + (wm * 64 + mt * 16 + r) * 32 + kseg);
        #pragma unroll
        for (int nt = 0; nt < 4; ++nt)
            b[nt] = *(const s16x8*)(sB + (wn * 64 + nt * 16 + r) * 32 + kseg);
        #pragma unroll
        for (int mt = 0; mt < 4; ++mt)
            #pragma unroll
            for (int nt = 0; nt < 4; ++nt)
                acc[mt][nt] = __builtin_amdgcn_mfma_f32_16x16x32_bf16(a[mt], b[nt], acc[mt][nt], 0, 0, 0);
    }
    int mrow0 = (lane >> 4) * 4;
    #pragma unroll
    for (int mt = 0; mt < 4; ++mt) {
        #pragma unroll
        for (int nt = 0; nt < 4; ++nt) {
            int m = blockIdx.y * 128 + wm * 64 + mt * 16 + mrow0;
            int n = blockIdx.x * 128 + wn * 64 + nt * 16 + r;
            float bv = bias[n];
            #pragma unroll
            for (int q = 0; q < 4; ++q)
                C[(size_t)(m + q) * N + n] = acc[mt][nt][q] + bv;
        }
    }
}

// ---------- logits GEMM: writes f32 to d_out with [t,b]->[b,t] row remap ----------
__global__ __launch_bounds__(256) void k_gemm_logits(
    const u16* __restrict__ A, const u16* __restrict__ Bt,
    const float* __restrict__ bias, float* __restrict__ C)
{
    const int K = 512, N = 32000;
    __shared__ u16 sA[128 * 32];
    __shared__ u16 sB[128 * 32];
    int tid = threadIdx.x;
    int wave = tid >> 6, lane = tid & 63;
    int wm = wave >> 1, wn = wave & 1;
    int r = lane & 15, kseg = (lane >> 4) * 8;
    const u16* Ab = A + (size_t)blockIdx.y * 128 * K;
    const u16* Bb = Bt + (size_t)blockIdx.x * 128 * K;
    f32x4 acc[4][4];
    f32x4 z = {0.f, 0.f, 0.f, 0.f};
    for (int mt = 0; mt < 4; ++mt)
        for (int nt = 0; nt < 4; ++nt) acc[mt][nt] = z;

    for (int kt = 0; kt < K; kt += 32) {
        __syncthreads();
        #pragma unroll
        for (int s = 0; s < 2; ++s) {
            int e = (s * 256 + tid) * 8;
            int row = e >> 5, kk = e & 31;
            __builtin_amdgcn_global_load_lds(
                (const AS1 void*)(Ab + (size_t)row * K + kt + kk),
                (AS3 void*)((char*)sA + s * 4096 + wave * 1024), 16, 0, 0);
            __builtin_amdgcn_global_load_lds(
                (const AS1 void*)(Bb + (size_t)row * K + kt + kk),
                (AS3 void*)((char*)sB + s * 4096 + wave * 1024), 16, 0, 0);
        }
        __syncthreads();
        s16x8 a[4], b[4];
        #pragma unroll
        for (int mt = 0; mt < 4; ++mt)
            a[mt] = *(const s16x8*)(sA + (wm * 64 + mt * 16 + r) * 32 + kseg);
        #pragma unroll
        for (int nt = 0; nt < 4; ++nt)
            b[nt] = *(const s16x8*)(sB + (wn * 64 + nt * 16 + r) * 32 + kseg);
        #pragma unroll
        for (int mt = 0; mt < 4; ++mt)
            #pragma unroll
            for (int nt = 0; nt < 4; ++nt)
                acc[mt][nt] = __builtin_amdgcn_mfma_f32_16x16x32_bf16(a[mt], b[nt], acc[mt][nt], 0, 0, 0);
    }
    int mrow0 = (lane >> 4) * 4;
    #pragma unroll
    for (int mt = 0; mt < 4; ++mt) {
        #pragma unroll
        for (int nt = 0; nt < 4; ++nt) {
            int n = blockIdx.x * 128 + wn * 64 + nt * 16 + r;
            float bv = bias[n];
            #pragma unroll
            for (int q = 0; q < 4; ++q) {
                int m = blockIdx.y * 128 + wm * 64 + mt * 16 + mrow0 + q;  // m = t*32 + b
                int row2 = (m & 31) * 64 + (m >> 5);                        // b*64 + t
                C[(size_t)row2 * N + n] = acc[mt][nt][q] + bv;
            }
        }
    }
}

// ---------- persistent LSTM scan: encoder (T=128) + decoder (T=64) in one kernel ----------
// 16 blocks x 256 threads. Block owns j-slice of 32 cols; wave g owns gate g.
// h crosses blocks via ping-pong global buffers accessed ONLY with agent-scope
// (sc1) relaxed atomics -> coherent at L3, no cache-wide fences anywhere.
__global__ __launch_bounds__(256, 1) void k_scan(
    const u16* __restrict__ UhTe, const u16* __restrict__ UhTd,
    const float* __restrict__ xgE, const float* __restrict__ xgD,
    const float* __restrict__ bhE, const float* __restrict__ bhD,
    u16* __restrict__ hping, u16* __restrict__ hs, int* __restrict__ bar)
{
    int tid = threadIdx.x, lane = tid & 63, g = tid >> 6;
    int blk = blockIdx.x;
    int r = lane & 15, hi = lane >> 4, kseg = hi * 8;
    int jbase = blk * 32;
    __shared__ float gsm[4][32][33];
    float cr[4] = {0.f, 0.f, 0.f, 0.f};
    int eb = tid >> 3;             // epilogue row b (0..31)
    int ejq = (tid & 7) * 4;       // epilogue col offset within slice (4 cols)
    int st = 0;
    for (int phase = 0; phase < 2; ++phase) {
        const u16*  UhT = phase ? UhTd : UhTe;
        const float* xg = phase ? xgD : xgE;
        const float* bh = phase ? bhD : bhE;
        int T = phase ? 64 : 128;
        s16x8 B[16][2];
        #pragma unroll
        for (int kt = 0; kt < 16; ++kt)
            #pragma unroll
            for (int nt = 0; nt < 2; ++nt)
                B[kt][nt] = *(const s16x8*)(UhT +
                    (size_t)(g * 512 + jbase + nt * 16 + r) * 512 + kt * 32 + kseg);
        float4 bhv[4];
        #pragma unroll
        for (int gg = 0; gg < 4; ++gg)
            bhv[gg] = *(const float4*)(bh + gg * 512 + jbase + ejq);

        for (int t = 0; t < T; ++t, ++st) {
            const u16* hin = hping + (st & 1) * (32 * 512);
            u16* hout = hping + ((st + 1) & 1) * (32 * 512);
            // prefetch this step's xg slice early (hides HBM latency under MFMA)
            const float* xgt = xg + (size_t)t * 32 * 2048 + eb * 2048 + jbase + ejq;
            float4 xv0 = *(const float4*)(xgt);
            float4 xv1 = *(const float4*)(xgt + 512);
            float4 xv2 = *(const float4*)(xgt + 1024);
            float4 xv3 = *(const float4*)(xgt + 1536);
            f32x4 z = {0.f, 0.f, 0.f, 0.f};
            f32x4 acc[2][2] = {{z, z}, {z, z}};
            #pragma unroll
            for (int kt = 0; kt < 16; ++kt) {
                s16x8 a0 = load_h16(hin + r * 512 + kt * 32 + kseg);
                s16x8 a1 = load_h16(hin + (16 + r) * 512 + kt * 32 + kseg);
                acc[0][0] = __builtin_amdgcn_mfma_f32_16x16x32_bf16(a0, B[kt][0], acc[0][0], 0, 0, 0);
                acc[0][1] = __builtin_amdgcn_mfma_f32_16x16x32_bf16(a0, B[kt][1], acc[0][1], 0, 0, 0);
                acc[1][0] = __builtin_amdgcn_mfma_f32_16x16x32_bf16(a1, B[kt][0], acc[1][0], 0, 0, 0);
                acc[1][1] = __builtin_amdgcn_mfma_f32_16x16x32_bf16(a1, B[kt][1], acc[1][1], 0, 0, 0);
            }
            #pragma unroll
            for (int mt = 0; mt < 2; ++mt)
                #pragma unroll
                for (int nt = 0; nt < 2; ++nt)
                    #pragma unroll
                    for (int q = 0; q < 4; ++q)
                        gsm[g][mt * 16 + hi * 4 + q][nt * 16 + r] = acc[mt][nt][q];
            __syncthreads();
            // epilogue: recombine gates, update c (registers), emit h
            u16 hnb[4];
            #pragma unroll
            for (int q = 0; q < 4; ++q) {
                float gi = gsm[0][eb][ejq + q] + ((const float*)&xv0)[q] + ((const float*)&bhv[0])[q];
                float gf = gsm[1][eb][ejq + q] + ((const float*)&xv1)[q] + ((const float*)&bhv[1])[q];
                float gG = gsm[2][eb][ejq + q] + ((const float*)&xv2)[q] + ((const float*)&bhv[2])[q];
                float go = gsm[3][eb][ejq + q] + ((const float*)&xv3)[q] + ((const float*)&bhv[3])[q];
                float iv = 1.f / (1.f + expf(-gi));
                float fv = 1.f / (1.f + expf(-gf));
                float gv = tanhf(gG);
                float ov = 1.f / (1.f + expf(-go));
                cr[q] = fv * cr[q] + iv * gv;
                hnb[q] = f2bf(ov * tanhf(cr[q]));
            }
            u32 w0 = (u32)hnb[0] | ((u32)hnb[1] << 16);
            u32 w1 = (u32)hnb[2] | ((u32)hnb[3] << 16);
            u32* hp = (u32*)(hout + eb * 512 + jbase + ejq);
            __hip_atomic_store(hp,     w0, __ATOMIC_RELAXED, __HIP_MEMORY_SCOPE_AGENT);
            __hip_atomic_store(hp + 1, w1, __ATOMIC_RELAXED, __HIP_MEMORY_SCOPE_AGENT);
            if (phase) {
                u32* hq = (u32*)(hs + (size_t)t * 32 * 512 + eb * 512 + jbase + ejq);
                hq[0] = w0; hq[1] = w1;
            }
            // grid barrier: syncthreads drains vmcnt (sc1 stores visible at L3),
            // then relaxed arrival + relaxed spin -- NO cache maintenance ops.
            __syncthreads();
            if (tid == 0) {
                __hip_atomic_fetch_add(bar, 1, __ATOMIC_RELAXED, __HIP_MEMORY_SCOPE_AGENT);
                int tgt = (st + 1) * 16;
                while (__hip_atomic_load(bar, __ATOMIC_RELAXED, __HIP_MEMORY_SCOPE_AGENT) < tgt)
                    __builtin_amdgcn_s_sleep(1);
            }
            __syncthreads();
        }
    }
}

// ---------- in-place row log-softmax over V=32000: online max+sum pass, subtract pass ----------
__global__ __launch_bounds__(256) void k_logsoftmax(float* __restrict__ out)
{
    __shared__ float redm[4], reds[4], lses;
    int row = blockIdx.x;
    float4* rp4 = (float4*)(out + (size_t)row * 32000);
    int tid = threadIdx.x, lane = tid & 63, wave = tid >> 6;
    float m = -1e30f, s = 0.f;
    for (int i = tid; i < 8000; i += 256) {
        float4 v = rp4[i];
        float mx = fmaxf(fmaxf(v.x, v.y), fmaxf(v.z, v.w));
        if (mx > m) { s *= expf(m - mx); m = mx; }
        s += expf(v.x - m) + expf(v.y - m) + expf(v.z - m) + expf(v.w - m);
    }
    #pragma unroll
    for (int o = 32; o; o >>= 1) {
        float om = __shfl_down(m, o);
        float os = __shfl_down(s, o);
        float nm = fmaxf(m, om);
        s = s * expf(m - nm) + os * expf(om - nm);
        m = nm;
    }
    if (lane == 0) { redm[wave] = m; reds[wave] = s; }
    __syncthreads();
    if (tid == 0) {
        float M = redm[0], S = reds[0];
        #pragma unroll
        for (int w = 1; w < 4; ++w) {
            float nm = fmaxf(M, redm[w]);
            S = S * expf(M - nm) + reds[w] * expf(redm[w] - nm);
            M = nm;
        }
        lses = M + logf(S);
    }
    __syncthreads();
    float lse = lses;
    for (int i = tid; i < 8000; i += 256) {
        float4 v = rp4[i];
        v.x -= lse; v.y -= lse; v.z -= lse; v.w -= lse;
        rp4[i] = v;
    }
}

extern "C" void kernel_launch(void* const* d_in, const int* in_sizes, int n_in,
                              void* d_out, int out_size, void* d_ws, size_t ws_size,
                              hipStream_t stream)
{
    const int*   src       = (const int*)d_in[0];
    const int*   tgt       = (const int*)d_in[1];
    const float* enc_embed = (const float*)d_in[2];
    const float* enc_Wx    = (const float*)d_in[3];
    const float* enc_bx    = (const float*)d_in[4];
    const float* enc_Uh    = (const float*)d_in[5];
    const float* enc_bh    = (const float*)d_in[6];
    const float* dec_embed = (const float*)d_in[7];
    const float* dec_Wx    = (const float*)d_in[8];
    const float* dec_bx    = (const float*)d_in[9];
    const float* dec_Uh    = (const float*)d_in[10];
    const float* dec_bh    = (const float*)d_in[11];
    const float* out_W     = (const float*)d_in[12];
    const float* out_b     = (const float*)d_in[13];
    float* out = (float*)d_out;

    char* ws = (char*)d_ws;
    size_t off = 0;
    auto alloc = [&](size_t bytes) { void* p = ws + off; off += (bytes + 255) & ~(size_t)255; return p; };
    u16*   WoT  = (u16*)alloc(32000ull * 512 * 2);
    u16*   WxTe = (u16*)alloc(2048ull * 512 * 2);
    u16*   UhTe = (u16*)alloc(2048ull * 512 * 2);
    u16*   WxTd = (u16*)alloc(2048ull * 512 * 2);
    u16*   UhTd = (u16*)alloc(2048ull * 512 * 2);
    u16*   embE = (u16*)alloc(4096ull * 512 * 2);
    u16*   embD = (u16*)alloc(2048ull * 512 * 2);
    float* xgE  = (float*)alloc(4096ull * 2048 * 4);
    float* xgD  = (float*)alloc(2048ull * 2048 * 4);
    u16*   hbuf = (u16*)alloc(2ull * 32 * 512 * 2);
    u16*   hs   = (u16*)alloc(64ull * 32 * 512 * 2);
    int*   bar  = (int*)alloc(256);

    // weight transposes f32 [K][N] -> bf16 [N][K]
    k_transpose_f32_to_bf16T<<<dim3(1000, 16), 256, 0, stream>>>(out_W, WoT, 512, 32000);
    k_transpose_f32_to_bf16T<<<dim3(64, 16),   256, 0, stream>>>(enc_Wx, WxTe, 512, 2048);
    k_transpose_f32_to_bf16T<<<dim3(64, 16),   256, 0, stream>>>(enc_Uh, UhTe, 512, 2048);
    k_transpose_f32_to_bf16T<<<dim3(64, 16),   256, 0, stream>>>(dec_Wx, WxTd, 512, 2048);
    k_transpose_f32_to_bf16T<<<dim3(64, 16),   256, 0, stream>>>(dec_Uh, UhTd, 512, 2048);
    // embedding gathers
    k_gather<<<4096, 256, 0, stream>>>(src, enc_embed, embE, 128);
    k_gather<<<2048, 256, 0, stream>>>(tgt, dec_embed, embD, 64);
    // input projections: xg = emb @ Wx + bx
    k_gemm_xg<<<dim3(16, 32), 256, 0, stream>>>(embE, WxTe, enc_bx, xgE, 2048);
    k_gemm_xg<<<dim3(16, 16), 256, 0, stream>>>(embD, WxTd, dec_bx, xgD, 2048);
    // init h0 and barrier counter
    hipMemsetAsync(hbuf, 0, 2 * 32 * 512 * 2, stream);
    hipMemsetAsync(bar, 0, 256, stream);
    // full recurrence in ONE kernel (128 enc + 64 dec steps)
    k_scan<<<16, 256, 0, stream>>>(UhTe, UhTd, xgE, xgD, enc_bh, dec_bh, hbuf, hs, bar);
    // logits into d_out (with [t,b]->[b,t] remap + bias), then in-place log-softmax
    k_gemm_logits<<<dim3(250, 16), 256, 0, stream>>>(hs, WoT, out_b, out);
    k_logsoftmax<<<2048, 256, 0, stream>>>(out);
}